// Round 4
// baseline (197.274 us; speedup 1.0000x reference)
//
#include <hip/hip_runtime.h>
#include <math.h>
#include <stdint.h>

#define NG 8
#define GS 2048
#define DM 512
#define NE 64
#define CAP 32
#define NROWS (NG * GS)                       // 16384 total rows (g,s)
#define COMBINE_ELEMS (33554432ull)           // 8*2048*64*32

typedef float f32x4 __attribute__((ext_vector_type(4)));

// ---------------------------------------------------------------------------
// JAX Threefry-2x32 (partitionable path): bits[i] = o0 ^ o1 of
// threefry2x32(key=(0,42), x=(hi(i)=0, lo(i)=i)).   [verified: round 1 pass]
// ---------------------------------------------------------------------------
__device__ __forceinline__ void threefry2x32(uint32_t k0, uint32_t k1,
                                             uint32_t x0, uint32_t x1,
                                             uint32_t& o0, uint32_t& o1) {
  uint32_t ks[3] = {k0, k1, k0 ^ k1 ^ 0x1BD11BDAu};
  x0 += ks[0];
  x1 += ks[1];
  const uint32_t rot[2][4] = {{13u, 15u, 26u, 6u}, {17u, 29u, 16u, 24u}};
#pragma unroll
  for (int i = 0; i < 5; ++i) {
#pragma unroll
    for (int j = 0; j < 4; ++j) {
      uint32_t r = rot[i & 1][j];
      x0 += x1;
      x1 = (x1 << r) | (x1 >> (32u - r));
      x1 ^= x0;
    }
    x0 += ks[(i + 1) % 3];
    x1 += ks[(i + 2) % 3] + (uint32_t)(i + 1);
  }
  o0 = x0;
  o1 = x1;
}

// XLA ErfInv (f32), Giles polynomial — constants bit-match xla math.cc.
__device__ __forceinline__ float erfinv_xla(float x) {
  float w = -log1pf(-x * x);
  float p;
  if (w < 5.0f) {
    w = w - 2.5f;
    p = 2.81022636e-08f;
    p = __fmaf_rn(p, w, 3.43273939e-07f);
    p = __fmaf_rn(p, w, -3.5233877e-06f);
    p = __fmaf_rn(p, w, -4.39150654e-06f);
    p = __fmaf_rn(p, w, 0.00021858087f);
    p = __fmaf_rn(p, w, -0.00125372503f);
    p = __fmaf_rn(p, w, -0.00417768164f);
    p = __fmaf_rn(p, w, 0.246640727f);
    p = __fmaf_rn(p, w, 1.50140941f);
  } else {
    w = sqrtf(w) - 3.0f;
    p = -0.000200214257f;
    p = __fmaf_rn(p, w, 0.000100950558f);
    p = __fmaf_rn(p, w, 0.00134934322f);
    p = __fmaf_rn(p, w, -0.00367342844f);
    p = __fmaf_rn(p, w, 0.00573950773f);
    p = __fmaf_rn(p, w, -0.0076224613f);
    p = __fmaf_rn(p, w, 0.00943887047f);
    p = __fmaf_rn(p, w, 1.00167406f);
    p = __fmaf_rn(p, w, 2.83297682f);
  }
  return p * x;
}

__device__ __forceinline__ float jax_normal(uint32_t idx) {
  uint32_t o0, o1;
  threefry2x32(0u, 42u, 0u, idx, o0, o1);
  uint32_t bits = o0 ^ o1;
  float f = __uint_as_float((bits >> 9) | 0x3f800000u) - 1.0f;  // [0,1)
  const float lo = __uint_as_float(0xBF7FFFFFu);                // -0.99999994
  float v = fmaxf(lo, f * 2.0f + lo);
  return __uint_as_float(0x3FB504F3u) * erfinv_xla(v);  // sqrt(2)_f32 * erfinv
}

// ---------------------------------------------------------------------------
// Kernel 0: zero the 256 MB output (harness poisons with 0xAA before timing).
// BW-floor bound (~40 us at ~6.9 TB/s).
// ---------------------------------------------------------------------------
__global__ __launch_bounds__(256) void zero_kernel(f32x4* __restrict__ p, int n4) {
  int i = blockIdx.x * blockDim.x + threadIdx.x;
  const int stride = gridDim.x * blockDim.x;
  const f32x4 z = {0.f, 0.f, 0.f, 0.f};
  for (; i < n4; i += stride) __builtin_nontemporal_store(z, &p[i]);
}

// ---------------------------------------------------------------------------
// Kernel 1: fused gating GEMM (fp64 accum) + threefry noise + fp64 softmax.
// NO LDS: x rows are wave-uniform addresses -> broadcast f32x4 global loads
// (1 txn/instr, L1/L2-served, VMEM pipe) instead of the contended LDS pipe.
// f64 accumulation order identical to round 3 -> bit-identical gates.
// Output written TRANSPOSED: gatesT[(g*64+e)*2048 + s] for coalesced topk.
// ---------------------------------------------------------------------------
#define RPB 16
__global__ __launch_bounds__(256) void gate_kernel(
    const float* __restrict__ x,    // (NROWS, 512)
    const float* __restrict__ Wt,   // (512, 64)
    float* __restrict__ gatesT) {   // (NG*NE, GS)
  const int e = threadIdx.x & 63;
  const int q = threadIdx.x >> 6;  // wave id 0..3
  const int rowb = blockIdx.x * RPB + q;  // this thread's rows: rowb + {0,4,8,12}

  const float* xr0 = x + (size_t)rowb * DM;

  double acc0 = 0.0, acc1 = 0.0, acc2 = 0.0, acc3 = 0.0;
#pragma unroll 2
  for (int d = 0; d < DM; d += 4) {
    const f32x4 x0 = *(const f32x4*)(xr0 + 0 * DM + d);
    const f32x4 x1 = *(const f32x4*)(xr0 + 4 * DM + d);
    const f32x4 x2 = *(const f32x4*)(xr0 + 8 * DM + d);
    const f32x4 x3 = *(const f32x4*)(xr0 + 12 * DM + d);
#pragma unroll
    for (int k = 0; k < 4; ++k) {
      const double w = (double)Wt[(d + k) * NE + e];
      acc0 += (double)x0[k] * w;
      acc1 += (double)x1[k] * w;
      acc2 += (double)x2[k] * w;
      acc3 += (double)x3[k] * w;
    }
  }

  const double accs[4] = {acc0, acc1, acc2, acc3};
#pragma unroll
  for (int j = 0; j < 4; ++j) {
    const int row = rowb + 4 * j;
    float logit = (float)accs[j];
    float noised = logit + 0.015625f * jax_normal((uint32_t)(row * NE + e));
    // fp64 softmax across the 64 lanes (one expert per lane)
    double v = (double)noised;
    double m = v;
#pragma unroll
    for (int off = 32; off; off >>= 1) m = fmax(m, __shfl_xor(m, off, 64));
    double ex = exp(v - m);
    double s = ex;
#pragma unroll
    for (int off = 32; off; off >>= 1) s += __shfl_xor(s, off, 64);
    const int g = row >> 11;          // row / GS
    const int ss = row & (GS - 1);    // row % GS
    gatesT[((size_t)(g * NE + e)) * GS + ss] = (float)(ex / s);
  }
}

// ---------------------------------------------------------------------------
// Kernel 2: one WAVE per (group, expert). gatesT row is contiguous ->
// 8 coalesced f32x4 loads/lane (lane stride 16 B). 2048 candidates in
// registers; iterative top-32 via per-lane scan + 6-step shfl_xor butterfly
// (max value, min index on ties — matches lax.top_k). No LDS, no barriers.
// Lane's element j = k*4+i holds s = k*256 + lane*4 + i (ascending in j).
// ---------------------------------------------------------------------------
__global__ __launch_bounds__(64) void topk_kernel(
    const float* __restrict__ gatesT,  // (NG*NE, GS)
    float* __restrict__ out) {         // combine ++ dispatch
  const int ge = blockIdx.x;  // == g*64 + e
  const int g = ge >> 6;
  const int e = ge & 63;
  const int lane = threadIdx.x;

  const float* base = gatesT + (size_t)ge * GS;
  float v[32];
#pragma unroll
  for (int k = 0; k < 8; ++k) {
    const f32x4 t = *(const f32x4*)(base + k * 256 + lane * 4);
#pragma unroll
    for (int i = 0; i < 4; ++i) v[k * 4 + i] = t[i];
  }

  float my_v = 0.0f;
  int my_s = 0;

  for (int c = 0; c < CAP; ++c) {
    // per-lane argmax over 32 registers; j ascending == s ascending,
    // strict > keeps the smallest s on ties.
    float bv = -1.0f;  // gates are strictly positive
    int bj = 0;
#pragma unroll
    for (int j = 0; j < 32; ++j) {
      const bool better = v[j] > bv;
      bv = better ? v[j] : bv;
      bj = better ? j : bj;
    }
    int bs = (bj >> 2) * 256 + lane * 4 + (bj & 3);
    // wave-wide reduce: max value, tie -> min s
#pragma unroll
    for (int off = 1; off < 64; off <<= 1) {
      const float ov = __shfl_xor(bv, off, 64);
      const int os = __shfl_xor(bs, off, 64);
      if (ov > bv || (ov == bv && os < bs)) { bv = ov; bs = os; }
    }
    // all lanes agree on (bv, bs); owner lane removes it (static idx)
    const bool owner = (lane == ((bs >> 2) & 63));
    const int jj = ((bs >> 8) << 2) | (bs & 3);
#pragma unroll
    for (int j = 0; j < 32; ++j) v[j] = (owner && j == jj) ? -1.0f : v[j];
    if (lane == c) { my_v = bv; my_s = bs; }
  }

  float* combine = out;                   // (G,S,E,C)
  float* dispatch = out + COMBINE_ELEMS;  // (G,E,C,S)
  if (lane < CAP) {
    combine[(((size_t)(g * GS + my_s)) * NE + e) * CAP + lane] = my_v;
    dispatch[(((size_t)(g * NE + e)) * CAP + lane) * GS + my_s] = 1.0f;
  }
}

extern "C" void kernel_launch(void* const* d_in, const int* in_sizes, int n_in,
                              void* d_out, int out_size, void* d_ws,
                              size_t ws_size, hipStream_t stream) {
  (void)in_sizes; (void)n_in; (void)ws_size;
  const float* x = (const float*)d_in[0];   // (8,2048,512) f32
  const float* Wt = (const float*)d_in[1];  // (512,64) f32
  float* out = (float*)d_out;
  float* gatesT = (float*)d_ws;             // (512, 2048) f32 = 4 MB scratch

  int n4 = out_size / 4;
  zero_kernel<<<4096, 256, 0, stream>>>((f32x4*)out, n4);
  gate_kernel<<<NROWS / RPB, 256, 0, stream>>>(x, Wt, gatesT);
  topk_kernel<<<NG * NE, 64, 0, stream>>>(gatesT, out);
}

// Round 5
// 139.792 us; speedup vs baseline: 1.4112x; 1.4112x over previous
//
#include <hip/hip_runtime.h>
#include <math.h>
#include <stdint.h>

#define NG 8
#define GS 2048
#define DM 512
#define NE 64
#define CAP 32
#define NROWS (NG * GS)                       // 16384 total rows (g,s)
#define COMBINE_ELEMS (33554432ull)           // 8*2048*64*32

#define GATE_BLOCKS 1024
#define ZERO_BLOCKS 2048
#define N4 16777216                           // 268435456 B / 16

typedef float f32x4 __attribute__((ext_vector_type(4)));

// ---------------------------------------------------------------------------
// JAX Threefry-2x32 (partitionable path): bits[i] = o0 ^ o1 of
// threefry2x32(key=(0,42), x=(hi(i)=0, lo(i)=i)).   [verified: rounds 1,3,4]
// ---------------------------------------------------------------------------
__device__ __forceinline__ void threefry2x32(uint32_t k0, uint32_t k1,
                                             uint32_t x0, uint32_t x1,
                                             uint32_t& o0, uint32_t& o1) {
  uint32_t ks[3] = {k0, k1, k0 ^ k1 ^ 0x1BD11BDAu};
  x0 += ks[0];
  x1 += ks[1];
  const uint32_t rot[2][4] = {{13u, 15u, 26u, 6u}, {17u, 29u, 16u, 24u}};
#pragma unroll
  for (int i = 0; i < 5; ++i) {
#pragma unroll
    for (int j = 0; j < 4; ++j) {
      uint32_t r = rot[i & 1][j];
      x0 += x1;
      x1 = (x1 << r) | (x1 >> (32u - r));
      x1 ^= x0;
    }
    x0 += ks[(i + 1) % 3];
    x1 += ks[(i + 2) % 3] + (uint32_t)(i + 1);
  }
  o0 = x0;
  o1 = x1;
}

// XLA ErfInv (f32), Giles polynomial — constants bit-match xla math.cc.
__device__ __forceinline__ float erfinv_xla(float x) {
  float w = -log1pf(-x * x);
  float p;
  if (w < 5.0f) {
    w = w - 2.5f;
    p = 2.81022636e-08f;
    p = __fmaf_rn(p, w, 3.43273939e-07f);
    p = __fmaf_rn(p, w, -3.5233877e-06f);
    p = __fmaf_rn(p, w, -4.39150654e-06f);
    p = __fmaf_rn(p, w, 0.00021858087f);
    p = __fmaf_rn(p, w, -0.00125372503f);
    p = __fmaf_rn(p, w, -0.00417768164f);
    p = __fmaf_rn(p, w, 0.246640727f);
    p = __fmaf_rn(p, w, 1.50140941f);
  } else {
    w = sqrtf(w) - 3.0f;
    p = -0.000200214257f;
    p = __fmaf_rn(p, w, 0.000100950558f);
    p = __fmaf_rn(p, w, 0.00134934322f);
    p = __fmaf_rn(p, w, -0.00367342844f);
    p = __fmaf_rn(p, w, 0.00573950773f);
    p = __fmaf_rn(p, w, -0.0076224613f);
    p = __fmaf_rn(p, w, 0.00943887047f);
    p = __fmaf_rn(p, w, 1.00167406f);
    p = __fmaf_rn(p, w, 2.83297682f);
  }
  return p * x;
}

__device__ __forceinline__ float jax_normal(uint32_t idx) {
  uint32_t o0, o1;
  threefry2x32(0u, 42u, 0u, idx, o0, o1);
  uint32_t bits = o0 ^ o1;
  float f = __uint_as_float((bits >> 9) | 0x3f800000u) - 1.0f;  // [0,1)
  const float lo = __uint_as_float(0xBF7FFFFFu);                // -0.99999994
  float v = fmaxf(lo, f * 2.0f + lo);
  return __uint_as_float(0x3FB504F3u) * erfinv_xla(v);  // sqrt(2)_f32 * erfinv
}

// ---------------------------------------------------------------------------
// Kernel 1 (fused): heterogeneous blocks.
//   bid % 3 == 0  -> gate block (round-3 internals: LDS-staged x, fp64 GEMM
//                    in identical accumulation order, threefry noise, fp64
//                    softmax; transposed store for coalesced topk)
//   bid % 3 != 0  -> zero block (grid-stride nontemporal f32x4 stores over
//                    the 268 MB output)
// Zero's HBM-store work overlaps gate's VALU/LDS work on co-resident CUs.
// ---------------------------------------------------------------------------
#define RPB 16
__global__ __launch_bounds__(256) void fused_kernel(
    const float* __restrict__ x,    // (NROWS, 512)
    const float* __restrict__ Wt,   // (512, 64)
    float* __restrict__ gatesT,     // (NG*NE, GS)
    f32x4* __restrict__ outv) {     // output as f32x4[N4]
  __shared__ float xs[RPB * DM];  // 32 KB (reserved by all blocks)
  const int bid = blockIdx.x;
  const int role = bid % 3;

  if (role != 0) {
    // ---- zero block ----
    const int zid = (bid / 3) * 2 + (role - 1);   // 0..ZERO_BLOCKS-1
    const f32x4 z = {0.f, 0.f, 0.f, 0.f};
    for (int i = zid * 256 + threadIdx.x; i < N4; i += ZERO_BLOCKS * 256)
      __builtin_nontemporal_store(z, &outv[i]);
    return;
  }

  // ---- gate block ----
  const int gid = bid / 3;           // 0..GATE_BLOCKS-1
  const int e = threadIdx.x & 63;
  const int q = threadIdx.x >> 6;    // wave id 0..3
  const int row0 = gid * RPB;

  // stage x tile (coalesced f32x4)
  const f32x4* src = (const f32x4*)(x + (size_t)row0 * DM);
  f32x4* dst = (f32x4*)xs;
  for (int i = threadIdx.x; i < RPB * (DM / 4); i += 256) dst[i] = src[i];
  __syncthreads();

  double acc0 = 0.0, acc1 = 0.0, acc2 = 0.0, acc3 = 0.0;
#pragma unroll 2
  for (int d = 0; d < DM; d += 4) {
    const f32x4 x0 = *(const f32x4*)&xs[(q + 0) * DM + d];
    const f32x4 x1 = *(const f32x4*)&xs[(q + 4) * DM + d];
    const f32x4 x2 = *(const f32x4*)&xs[(q + 8) * DM + d];
    const f32x4 x3 = *(const f32x4*)&xs[(q + 12) * DM + d];
#pragma unroll
    for (int k = 0; k < 4; ++k) {
      const double w = (double)Wt[(d + k) * NE + e];
      acc0 += (double)x0[k] * w;
      acc1 += (double)x1[k] * w;
      acc2 += (double)x2[k] * w;
      acc3 += (double)x3[k] * w;
    }
  }

  const double accs[4] = {acc0, acc1, acc2, acc3};
#pragma unroll
  for (int j = 0; j < 4; ++j) {
    const int row = row0 + q + 4 * j;
    float logit = (float)accs[j];
    float noised = logit + 0.015625f * jax_normal((uint32_t)(row * NE + e));
    // fp64 softmax across the 64 lanes (one expert per lane)
    double v = (double)noised;
    double m = v;
#pragma unroll
    for (int off = 32; off; off >>= 1) m = fmax(m, __shfl_xor(m, off, 64));
    double ex = exp(v - m);
    double s = ex;
#pragma unroll
    for (int off = 32; off; off >>= 1) s += __shfl_xor(s, off, 64);
    const int g = row >> 11;          // row / GS
    const int ss = row & (GS - 1);    // row % GS
    gatesT[((size_t)(g * NE + e)) * GS + ss] = (float)(ex / s);
  }
}

// ---------------------------------------------------------------------------
// Kernel 2: one WAVE per (group, expert). gatesT row contiguous -> 8
// coalesced f32x4 loads/lane. 2048 candidates in registers; iterative top-32
// via per-lane scan + 6-step shfl_xor butterfly (max value, min index on
// ties — matches lax.top_k). No LDS, no barriers.  [verified: round 4]
// ---------------------------------------------------------------------------
__global__ __launch_bounds__(64) void topk_kernel(
    const float* __restrict__ gatesT,  // (NG*NE, GS)
    float* __restrict__ out) {         // combine ++ dispatch
  const int ge = blockIdx.x;  // == g*64 + e
  const int g = ge >> 6;
  const int e = ge & 63;
  const int lane = threadIdx.x;

  const float* base = gatesT + (size_t)ge * GS;
  float v[32];
#pragma unroll
  for (int k = 0; k < 8; ++k) {
    const f32x4 t = *(const f32x4*)(base + k * 256 + lane * 4);
#pragma unroll
    for (int i = 0; i < 4; ++i) v[k * 4 + i] = t[i];
  }

  float my_v = 0.0f;
  int my_s = 0;

  for (int c = 0; c < CAP; ++c) {
    float bv = -1.0f;  // gates are strictly positive
    int bj = 0;
#pragma unroll
    for (int j = 0; j < 32; ++j) {
      const bool better = v[j] > bv;
      bv = better ? v[j] : bv;
      bj = better ? j : bj;
    }
    int bs = (bj >> 2) * 256 + lane * 4 + (bj & 3);
#pragma unroll
    for (int off = 1; off < 64; off <<= 1) {
      const float ov = __shfl_xor(bv, off, 64);
      const int os = __shfl_xor(bs, off, 64);
      if (ov > bv || (ov == bv && os < bs)) { bv = ov; bs = os; }
    }
    const bool owner = (lane == ((bs >> 2) & 63));
    const int jj = ((bs >> 8) << 2) | (bs & 3);
#pragma unroll
    for (int j = 0; j < 32; ++j) v[j] = (owner && j == jj) ? -1.0f : v[j];
    if (lane == c) { my_v = bv; my_s = bs; }
  }

  float* combine = out;                   // (G,S,E,C)
  float* dispatch = out + COMBINE_ELEMS;  // (G,E,C,S)
  if (lane < CAP) {
    combine[(((size_t)(g * GS + my_s)) * NE + e) * CAP + lane] = my_v;
    dispatch[(((size_t)(g * NE + e)) * CAP + lane) * GS + my_s] = 1.0f;
  }
}

extern "C" void kernel_launch(void* const* d_in, const int* in_sizes, int n_in,
                              void* d_out, int out_size, void* d_ws,
                              size_t ws_size, hipStream_t stream) {
  (void)in_sizes; (void)n_in; (void)ws_size; (void)out_size;
  const float* x = (const float*)d_in[0];   // (8,2048,512) f32
  const float* Wt = (const float*)d_in[1];  // (512,64) f32
  float* out = (float*)d_out;
  float* gatesT = (float*)d_ws;             // (512, 2048) f32 = 4 MB scratch

  fused_kernel<<<GATE_BLOCKS + ZERO_BLOCKS, 256, 0, stream>>>(
      x, Wt, gatesT, (f32x4*)out);
  topk_kernel<<<NG * NE, 64, 0, stream>>>(gatesT, out);
}